// Round 5
// baseline (19979.764 us; speedup 1.0000x reference)
//
#include <hip/hip_runtime.h>
#include <hip/hip_bf16.h>
#include <cstdint>

#define TENC 100
#define TDEC 25
#define BATCH 512
#define DIN 96
#define HDIM 1024

// quaternion multiplication tables for qlinear:
// out_comp = sum_c sgn[comp][c] * x_c @ W[widx[comp][c]]
__device__ __constant__ int q_widx[4][4] = {{0,1,2,3},{1,0,3,2},{2,3,0,1},{3,2,1,0}};
__device__ __constant__ float q_sgn[4][4] = {{1.f,-1.f,-1.f,-1.f},
                                             {1.f, 1.f, 1.f,-1.f},
                                             {1.f,-1.f, 1.f, 1.f},
                                             {1.f, 1.f,-1.f, 1.f}};

// Build effective matrix M [4*nin x 4*nout] from W [4, nin, nout]:
// M[c*nin+m][comp*nout+o] = sgn[comp][c] * W[widx[comp][c]][m][o]
// (multiplication by +-1.0 is exact; negation commutes with IEEE rounding)
__global__ void build_eff_kernel(const float* __restrict__ W, float* __restrict__ M,
                                 int nin, int nout) {
    int idx = blockIdx.x * blockDim.x + threadIdx.x;
    int ncol = nout * 4;
    int total = nin * 4 * ncol;
    if (idx >= total) return;
    int col = idx % ncol;
    int k = idx / ncol;
    int c = k / nin, m = k - c * nin;
    int comp = col / nout, o = col - comp * nout;
    M[idx] = q_sgn[comp][c] * W[(size_t)(q_widx[comp][c] * nin + m) * nout + o];
}

// XLA-CPU f32 tanh: Eigen-derived rational polynomial as emitted by XLA's
// elemental IR emitter (plain mul/add, no contraction), tiny-x passthrough,
// +-7.99881172180175781 clamp.  (verified: R4 passed with this exact fn)
__device__ inline float xla_tanh(float x) {
    float ax = fabsf(x);
    if (ax < 0.0004f) return x;
    float t = fminf(fmaxf(x, -7.99881172180175781f), 7.99881172180175781f);
    float x2 = __fmul_rn(t, t);
    float p = -2.76076847742355e-16f;
    p = __fadd_rn(__fmul_rn(p, x2), 2.00018790482477e-13f);
    p = __fadd_rn(__fmul_rn(p, x2), -8.60467152213735e-11f);
    p = __fadd_rn(__fmul_rn(p, x2), 5.12229709037114e-08f);
    p = __fadd_rn(__fmul_rn(p, x2), 1.48572235717979e-05f);
    p = __fadd_rn(__fmul_rn(p, x2), 6.37261928875436e-04f);
    p = __fadd_rn(__fmul_rn(p, x2), 4.89352455891786e-03f);
    float num = __fmul_rn(t, p);
    float q = 1.19825839466702e-06f;
    q = __fadd_rn(__fmul_rn(q, x2), 1.18534705686654e-04f);
    q = __fadd_rn(__fmul_rn(q, x2), 2.26843463243900e-03f);
    q = __fadd_rn(__fmul_rn(q, x2), 4.89352518554385e-03f);
    return __fdiv_rn(num, q);
}

// One RNN step: Hout = xla_tanh( (x@Mx chains + bx) + h@Mh chains )
// Chain structure identical to R4 (bit-exact): per c-block, single ascending-k
// acc=add(acc,mul) chain; c-blocks combined left-assoc starting from 0;
// rs = (xcb + bias) + hcb; then tanh.
// Tile 32x32, 256 threads, micro 2x2, grid (1024/32, 512/32) = (32,16) = 512 wg.
__global__ __launch_bounds__(256)
void rnn_step(const float* __restrict__ X,     // [512][96]
              const float* __restrict__ Hin,   // [512][1024]
              const float* __restrict__ Mx,    // [96][1024]
              const float* __restrict__ Mh,    // [1024][1024]
              const float* __restrict__ bx,    // [1024]
              float* __restrict__ Hout) {      // [512][1024]
    __shared__ float lds[6272];
    float* Xs  = lds;            // [32][100]  (pad 100: rows land on distinct banks)
    float* Bxs = lds + 3200;     // [96][32]
    float* As  = lds;            // [64][34]   (aliases Xs after x-phase)
    float* Bs  = lds + 2176;     // [64][32]

    const int tid = threadIdx.x;
    const int tx = tid & 15, ty = tid >> 4;
    const int c0 = blockIdx.x * 32;
    const int r0 = blockIdx.y * 32;

    // ---- stage x tile [32][96] and Mx tile [96][32] ----
    #pragma unroll
    for (int i = 0; i < 12; ++i) {
        int idx = tid + 256 * i;
        int row = idx / 96, k = idx - row * 96;
        Xs[row * 100 + k] = X[(size_t)(r0 + row) * 96 + k];
    }
    #pragma unroll
    for (int i = 0; i < 12; ++i) {
        int idx = tid + 256 * i;
        int k = idx >> 5, c = idx & 31;
        Bxs[k * 32 + c] = Mx[(size_t)k * 1024 + c0 + c];
    }
    __syncthreads();

    // ---- x-pass: 4 chains of length 24, combined left-assoc ----
    float xcb[2][2] = {{0.f, 0.f}, {0.f, 0.f}};
    #pragma unroll
    for (int cb = 0; cb < 4; ++cb) {
        float xa[2][2] = {{0.f, 0.f}, {0.f, 0.f}};
        #pragma unroll
        for (int kk = 0; kk < 24; ++kk) {
            int K = cb * 24 + kk;
            float a0 = Xs[(ty * 2 + 0) * 100 + K];
            float a1 = Xs[(ty * 2 + 1) * 100 + K];
            float2 b = *reinterpret_cast<const float2*>(&Bxs[K * 32 + tx * 2]);
            xa[0][0] = __fadd_rn(xa[0][0], __fmul_rn(a0, b.x));
            xa[0][1] = __fadd_rn(xa[0][1], __fmul_rn(a0, b.y));
            xa[1][0] = __fadd_rn(xa[1][0], __fmul_rn(a1, b.x));
            xa[1][1] = __fadd_rn(xa[1][1], __fmul_rn(a1, b.y));
        }
        #pragma unroll
        for (int i = 0; i < 2; ++i)
            #pragma unroll
            for (int j = 0; j < 2; ++j)
                xcb[i][j] = __fadd_rn(xcb[i][j], xa[i][j]);
    }
    // rs = xcb + bias
    float2 bb = *reinterpret_cast<const float2*>(&bx[c0 + tx * 2]);
    float rs[2][2];
    #pragma unroll
    for (int i = 0; i < 2; ++i) {
        rs[i][0] = __fadd_rn(xcb[i][0], bb.x);
        rs[i][1] = __fadd_rn(xcb[i][1], bb.y);
    }

    // ---- h-pass: K=1024 in 16 chunks of 64; c-block = 4 chunks ----
    float hcb[2][2] = {{0.f, 0.f}, {0.f, 0.f}};
    float ha[2][2]  = {{0.f, 0.f}, {0.f, 0.f}};
    for (int kb = 0; kb < 16; ++kb) {
        __syncthreads();   // also guards Xs/Bxs -> As/Bs alias on kb==0
        {
            int lk = tid & 63, lr0 = tid >> 6;
            #pragma unroll
            for (int i = 0; i < 8; ++i) {
                int row = lr0 + 4 * i;
                As[lk * 34 + row] = Hin[(size_t)(r0 + row) * 1024 + kb * 64 + lk];
            }
        }
        {
            int lc = tid & 31, lk0 = tid >> 5;
            #pragma unroll
            for (int i = 0; i < 8; ++i) {
                int k = lk0 + 8 * i;
                Bs[k * 32 + lc] = Mh[(size_t)(kb * 64 + k) * 1024 + c0 + lc];
            }
        }
        __syncthreads();
        #pragma unroll 8
        for (int k = 0; k < 64; ++k) {
            float2 a = *reinterpret_cast<const float2*>(&As[k * 34 + ty * 2]);
            float2 b = *reinterpret_cast<const float2*>(&Bs[k * 32 + tx * 2]);
            ha[0][0] = __fadd_rn(ha[0][0], __fmul_rn(a.x, b.x));
            ha[0][1] = __fadd_rn(ha[0][1], __fmul_rn(a.x, b.y));
            ha[1][0] = __fadd_rn(ha[1][0], __fmul_rn(a.y, b.x));
            ha[1][1] = __fadd_rn(ha[1][1], __fmul_rn(a.y, b.y));
        }
        if ((kb & 3) == 3) {   // finished one c-block chain: fold left-assoc
            #pragma unroll
            for (int i = 0; i < 2; ++i)
                #pragma unroll
                for (int j = 0; j < 2; ++j) {
                    hcb[i][j] = __fadd_rn(hcb[i][j], ha[i][j]);
                    ha[i][j] = 0.f;
                }
        }
    }

    // ---- rs = rs + hcb; tanh; store ----
    #pragma unroll
    for (int i = 0; i < 2; ++i) {
        float v0 = xla_tanh(__fadd_rn(rs[i][0], hcb[i][0]));
        float v1 = xla_tanh(__fadd_rn(rs[i][1], hcb[i][1]));
        *reinterpret_cast<float2*>(
            &Hout[(size_t)(r0 + ty * 2 + i) * 1024 + c0 + tx * 2]) =
            make_float2(v0, v1);
    }
}

// Fused predict head: pred = h@Ml chains + bl, then per-quaternion
// normalize + Hamilton product with `pre`, write out.  Chain structure and
// qmul expression trees identical to R4 (bit-exact).
// Tile 32 rows x 96 cols (full N), 256 threads, micro 2x6. grid = Mrows/32.
__global__ __launch_bounds__(256)
void predict_qmul(const float* __restrict__ H,    // [M][1024]
                  const float* __restrict__ Ml,   // [1024][96]
                  const float* __restrict__ bl,   // [96]
                  const float* __restrict__ pre,  // [M][96]
                  float* __restrict__ out) {      // [M][96]
    __shared__ float lds[8576];
    float* As = lds;             // [64][34]
    float* Bs = lds + 2176;      // [64][100]
    float* Ps = lds;             // [32][100] (aliases As+Bs head after GEMM)

    const int tid = threadIdx.x;
    const int tx = tid & 15, ty = tid >> 4;
    const int r0 = blockIdx.x * 32;

    float hcb[2][6], ha[2][6];
    #pragma unroll
    for (int i = 0; i < 2; ++i)
        #pragma unroll
        for (int j = 0; j < 6; ++j) { hcb[i][j] = 0.f; ha[i][j] = 0.f; }

    for (int kb = 0; kb < 16; ++kb) {
        __syncthreads();
        {
            int lk = tid & 63, lr0 = tid >> 6;
            #pragma unroll
            for (int i = 0; i < 8; ++i) {
                int row = lr0 + 4 * i;
                As[lk * 34 + row] = H[(size_t)(r0 + row) * 1024 + kb * 64 + lk];
            }
        }
        #pragma unroll
        for (int i = 0; i < 24; ++i) {
            int idx = tid + 256 * i;
            int k = idx / 96, c = idx - k * 96;
            Bs[k * 100 + c] = Ml[(size_t)(kb * 64 + k) * 96 + c];
        }
        __syncthreads();
        #pragma unroll 4
        for (int k = 0; k < 64; ++k) {
            float2 a = *reinterpret_cast<const float2*>(&As[k * 34 + ty * 2]);
            const float* bp = &Bs[k * 100 + tx * 6];
            float2 b0 = *reinterpret_cast<const float2*>(bp);
            float2 b1 = *reinterpret_cast<const float2*>(bp + 2);
            float2 b2 = *reinterpret_cast<const float2*>(bp + 4);
            float bv[6] = {b0.x, b0.y, b1.x, b1.y, b2.x, b2.y};
            #pragma unroll
            for (int j = 0; j < 6; ++j) {
                ha[0][j] = __fadd_rn(ha[0][j], __fmul_rn(a.x, bv[j]));
                ha[1][j] = __fadd_rn(ha[1][j], __fmul_rn(a.y, bv[j]));
            }
        }
        if ((kb & 3) == 3) {
            #pragma unroll
            for (int i = 0; i < 2; ++i)
                #pragma unroll
                for (int j = 0; j < 6; ++j) {
                    hcb[i][j] = __fadd_rn(hcb[i][j], ha[i][j]);
                    ha[i][j] = 0.f;
                }
        }
    }

    __syncthreads();   // all As/Bs reads done before Ps alias write
    #pragma unroll
    for (int i = 0; i < 2; ++i)
        #pragma unroll
        for (int j = 0; j < 6; ++j) {
            int c = tx * 6 + j;
            Ps[(ty * 2 + i) * 100 + c] = __fadd_rn(hcb[i][j], bl[c]);
        }
    __syncthreads();

    // per-quaternion normalize + Hamilton product (exact R4 expression trees)
    #pragma unroll
    for (int i = 0; i < 3; ++i) {
        int q = tid + 256 * i;          // 0..767
        int row = q / 24, n = q - row * 24;
        const float* p = &Ps[row * 100 + n];
        float pw = p[0], px = p[24], py = p[48], pz = p[72];
        float s = __fadd_rn(__fadd_rn(__fadd_rn(__fmul_rn(pw, pw), __fmul_rn(px, px)),
                                      __fmul_rn(py, py)), __fmul_rn(pz, pz));
        float nr = sqrtf(s);
        float nm = fmaxf(nr, 1e-12f);
        pw = __fdiv_rn(pw, nm); px = __fdiv_rn(px, nm);
        py = __fdiv_rn(py, nm); pz = __fdiv_rn(pz, nm);
        const float* r = pre + (size_t)(r0 + row) * 96 + n;
        float rw = r[0], rx = r[24], ry = r[48], rz = r[72];
        float* o = out + (size_t)(r0 + row) * 96 + n;
        o[0]  = __fsub_rn(__fsub_rn(__fsub_rn(__fmul_rn(pw, rw), __fmul_rn(px, rx)),
                                    __fmul_rn(py, ry)), __fmul_rn(pz, rz));
        o[24] = __fsub_rn(__fadd_rn(__fadd_rn(__fmul_rn(pw, rx), __fmul_rn(px, rw)),
                                    __fmul_rn(py, rz)), __fmul_rn(pz, ry));
        o[48] = __fadd_rn(__fadd_rn(__fsub_rn(__fmul_rn(pw, ry), __fmul_rn(px, rz)),
                                    __fmul_rn(py, rw)), __fmul_rn(pz, rx));
        o[72] = __fadd_rn(__fsub_rn(__fadd_rn(__fmul_rn(pw, rz), __fmul_rn(px, ry)),
                                    __fmul_rn(py, rx)), __fmul_rn(pz, rw));
    }
}

extern "C" void kernel_launch(void* const* d_in, const int* in_sizes, int n_in,
                              void* d_out, int out_size, void* d_ws, size_t ws_size,
                              hipStream_t stream) {
    const float* inp    = (const float*)d_in[0];  // [100,512,96]
    const float* target = (const float*)d_in[1];  // [26,512,96]
    const float* Wx     = (const float*)d_in[2];  // [4,24,256]
    const float* bx     = (const float*)d_in[3];  // [1024]
    const float* Wh     = (const float*)d_in[4];  // [4,256,256]
    const float* Wl     = (const float*)d_in[5];  // [4,256,24]
    const float* bl     = (const float*)d_in[6];  // [96]

    float* out = (float*)d_out;
    float* out_enc = out;                                   // [100,512,96]
    float* out_dec = out + (size_t)TENC * BATCH * DIN;      // [25,512,96]

    const size_t SH = (size_t)BATCH * HDIM;    // 524288
    const size_t SX = (size_t)BATCH * DIN;     // 49152

    size_t off = 0;
    auto alloc = [&](size_t nf) -> float* {
        float* p = (float*)((char*)d_ws + off);
        off += nf * sizeof(float);
        return p;
    };
    float* M_x = alloc((size_t)DIN * HDIM);    // 96 x 1024
    float* M_h = alloc((size_t)HDIM * HDIM);   // 1024 x 1024
    float* M_l = alloc((size_t)HDIM * DIN);    // 1024 x 96
    float* hs  = alloc((size_t)(TENC + 1) * SH);  // h_0..h_100 (~207 MB total)

    // ---- build effective matrices ----
    {
        int t1 = 4 * 24 * 4 * 256;
        build_eff_kernel<<<(t1 + 255) / 256, 256, 0, stream>>>(Wx, M_x, 24, 256);
        int t2 = 4 * 256 * 4 * 256;
        build_eff_kernel<<<(t2 + 255) / 256, 256, 0, stream>>>(Wh, M_h, 256, 256);
        int t3 = 4 * 256 * 4 * 24;
        build_eff_kernel<<<(t3 + 255) / 256, 256, 0, stream>>>(Wl, M_l, 256, 24);
    }

    hipMemsetAsync(hs, 0, SH * sizeof(float), stream);  // h0 = 0

    dim3 gRnn(HDIM / 32, BATCH / 32);   // (32, 16) = 512 wg

    // ---- encoder ----
    for (int t = 0; t < TENC; ++t) {
        rnn_step<<<gRnn, 256, 0, stream>>>(
            inp + (size_t)t * SX, hs + (size_t)t * SH,
            M_x, M_h, bx, hs + (size_t)(t + 1) * SH);
    }
    // batched predict over all 100 steps
    predict_qmul<<<(TENC * BATCH) / 32, 256, 0, stream>>>(
        hs + SH, M_l, bl, inp, out_enc);

    // ---- decoder (ping-pong in hs slots 0/1; hs[1..100] no longer needed) ----
    const float* x = target;            // target[0]
    float* hin = hs + (size_t)TENC * SH;
    for (int t = 0; t < TDEC; ++t) {
        float* hout = (t & 1) ? (hs + SH) : hs;
        rnn_step<<<gRnn, 256, 0, stream>>>(x, hin, M_x, M_h, bx, hout);
        predict_qmul<<<BATCH / 32, 256, 0, stream>>>(
            hout, M_l, bl, x, out_dec + (size_t)t * SX);
        x = out_dec + (size_t)t * SX;
        hin = hout;
    }
}

// Round 6
// 4972.965 us; speedup vs baseline: 4.0177x; 4.0177x over previous
//
#include <hip/hip_runtime.h>
#include <hip/hip_bf16.h>
#include <cstdint>

#define TENC 100
#define TDEC 25
#define BATCH 512
#define DIN 96
#define HDIM 1024

__device__ __constant__ int q_widx[4][4] = {{0,1,2,3},{1,0,3,2},{2,3,0,1},{3,2,1,0}};
__device__ __constant__ float q_sgn[4][4] = {{1.f,-1.f,-1.f,-1.f},
                                             {1.f, 1.f, 1.f,-1.f},
                                             {1.f,-1.f, 1.f, 1.f},
                                             {1.f, 1.f,-1.f, 1.f}};

// M[c*nin+m][comp*nout+o] = sgn[comp][c] * W[widx[comp][c]][m][o]
__global__ void build_eff_kernel(const float* __restrict__ W, float* __restrict__ M,
                                 int nin, int nout) {
    int idx = blockIdx.x * blockDim.x + threadIdx.x;
    int ncol = nout * 4;
    int total = nin * 4 * ncol;
    if (idx >= total) return;
    int col = idx % ncol;
    int k = idx / ncol;
    int c = k / nin, m = k - c * nin;
    int comp = col / nout, o = col - comp * nout;
    M[idx] = q_sgn[comp][c] * W[(size_t)(q_widx[comp][c] * nin + m) * nout + o];
}

// XLA-CPU f32 tanh (verified bit-matching in R4/R5)
__device__ inline float xla_tanh(float x) {
    float ax = fabsf(x);
    if (ax < 0.0004f) return x;
    float t = fminf(fmaxf(x, -7.99881172180175781f), 7.99881172180175781f);
    float x2 = __fmul_rn(t, t);
    float p = -2.76076847742355e-16f;
    p = __fadd_rn(__fmul_rn(p, x2), 2.00018790482477e-13f);
    p = __fadd_rn(__fmul_rn(p, x2), -8.60467152213735e-11f);
    p = __fadd_rn(__fmul_rn(p, x2), 5.12229709037114e-08f);
    p = __fadd_rn(__fmul_rn(p, x2), 1.48572235717979e-05f);
    p = __fadd_rn(__fmul_rn(p, x2), 6.37261928875436e-04f);
    p = __fadd_rn(__fmul_rn(p, x2), 4.89352455891786e-03f);
    float num = __fmul_rn(t, p);
    float q = 1.19825839466702e-06f;
    q = __fadd_rn(__fmul_rn(q, x2), 1.18534705686654e-04f);
    q = __fadd_rn(__fmul_rn(q, x2), 2.26843463243900e-03f);
    q = __fadd_rn(__fmul_rn(q, x2), 4.89352518554385e-03f);
    return __fdiv_rn(num, q);
}

// RNN-step partials.  z<4: part[z] = single ascending-k chain over
// K-window [z*256, z*256+256) of Hin@Mh (R4's per-c-block chain, bit-exact).
// z==4: part[4] = xcb = ((x0+x1)+x2)+x3 (R4 pass-0, 4 chains of 24).
// Structure = R4's gemm_xla core: 64x64 tile, 256 thr, 4x4 micro (~52 VGPR).
__global__ __launch_bounds__(256)
void rnn_part(const float* __restrict__ X,     // [512][96]
              const float* __restrict__ Hin,   // [512][1024]
              const float* __restrict__ Mx,    // [96][1024]
              const float* __restrict__ Mh,    // [1024][1024]
              float* __restrict__ part) {      // [5][512*1024]
    __shared__ __align__(16) float As[64][68];
    __shared__ __align__(16) float Bs[64][64];

    const int tid = threadIdx.x;
    const int tx = tid & 15, ty = tid >> 4;
    const int c0 = blockIdx.x * 64;
    const int r0 = blockIdx.y * 64;
    const int z  = blockIdx.z;
    const int lk = tid & 63, lr = tid >> 6;

    float acc[4][4];
    #pragma unroll
    for (int i = 0; i < 4; ++i)
        #pragma unroll
        for (int j = 0; j < 4; ++j) acc[i][j] = 0.f;

    if (z < 4) {
        // single chain, K = 256 in 4 chunks of 64, NO intermediate folds
        for (int kb = 0; kb < 4; ++kb) {
            const int k0 = z * 256 + kb * 64;
            __syncthreads();
            {
                const float* ap = Hin + (size_t)(r0 + lr) * 1024 + k0 + lk;
                #pragma unroll
                for (int i = 0; i < 16; ++i)
                    As[lk][lr + 4 * i] = ap[(size_t)(4 * i) * 1024];
            }
            {
                const int ccol = c0 + lk;
                #pragma unroll
                for (int i = 0; i < 16; ++i) {
                    int k = lr + 4 * i;
                    Bs[k][lk] = Mh[(size_t)(k0 + k) * 1024 + ccol];
                }
            }
            __syncthreads();
            #pragma unroll 8
            for (int k = 0; k < 64; ++k) {
                float4 av = *reinterpret_cast<const float4*>(&As[k][ty * 4]);
                float4 bv = *reinterpret_cast<const float4*>(&Bs[k][tx * 4]);
                float aa[4] = {av.x, av.y, av.z, av.w};
                float bb[4] = {bv.x, bv.y, bv.z, bv.w};
                #pragma unroll
                for (int i = 0; i < 4; ++i)
                    #pragma unroll
                    for (int j = 0; j < 4; ++j)
                        acc[i][j] = __fadd_rn(acc[i][j], __fmul_rn(aa[i], bb[j]));
            }
        }
    } else {
        // x-pass: 4 chains of 24, folded left-assoc (R4 pass-0, bit-exact)
        for (int c = 0; c < 4; ++c) {
            float xa[4][4];
            #pragma unroll
            for (int i = 0; i < 4; ++i)
                #pragma unroll
                for (int j = 0; j < 4; ++j) xa[i][j] = 0.f;
            const int k0 = c * 24;
            __syncthreads();
            if (lk < 24) {
                const float* ap = X + (size_t)(r0 + lr) * 96 + k0 + lk;
                #pragma unroll
                for (int i = 0; i < 16; ++i)
                    As[lk][lr + 4 * i] = ap[(size_t)(4 * i) * 96];
            }
            {
                const int ccol = c0 + lk;
                #pragma unroll
                for (int i = 0; i < 16; ++i) {
                    int k = lr + 4 * i;
                    if (k < 24)
                        Bs[k][lk] = Mx[(size_t)(k0 + k) * 1024 + ccol];
                }
            }
            __syncthreads();
            #pragma unroll 4
            for (int k = 0; k < 24; ++k) {
                float4 av = *reinterpret_cast<const float4*>(&As[k][ty * 4]);
                float4 bv = *reinterpret_cast<const float4*>(&Bs[k][tx * 4]);
                float aa[4] = {av.x, av.y, av.z, av.w};
                float bb[4] = {bv.x, bv.y, bv.z, bv.w};
                #pragma unroll
                for (int i = 0; i < 4; ++i)
                    #pragma unroll
                    for (int j = 0; j < 4; ++j)
                        xa[i][j] = __fadd_rn(xa[i][j], __fmul_rn(aa[i], bb[j]));
            }
            #pragma unroll
            for (int i = 0; i < 4; ++i)
                #pragma unroll
                for (int j = 0; j < 4; ++j)
                    acc[i][j] = __fadd_rn(acc[i][j], xa[i][j]);
        }
    }

    float* pp = part + (size_t)z * (BATCH * HDIM);
    const int ccol = c0 + tx * 4;
    #pragma unroll
    for (int i = 0; i < 4; ++i) {
        int r = r0 + ty * 4 + i;
        *reinterpret_cast<float4*>(pp + (size_t)r * 1024 + ccol) =
            make_float4(acc[i][0], acc[i][1], acc[i][2], acc[i][3]);
    }
}

// Hout = xla_tanh( (x_part + bx) + (((h0+h1)+h2)+h3) )   -- exact R4 fold order
__global__ __launch_bounds__(256)
void rnn_combine(const float* __restrict__ part, const float* __restrict__ bx,
                 float* __restrict__ Hout) {
    int t = blockIdx.x * blockDim.x + threadIdx.x;   // 131072 threads, float4 each
    int i = t * 4;
    int col = i & 1023;
    const size_t SH = (size_t)BATCH * HDIM;
    float4 xp = *reinterpret_cast<const float4*>(part + 4 * SH + i);
    float4 h0 = *reinterpret_cast<const float4*>(part + 0 * SH + i);
    float4 h1 = *reinterpret_cast<const float4*>(part + 1 * SH + i);
    float4 h2 = *reinterpret_cast<const float4*>(part + 2 * SH + i);
    float4 h3 = *reinterpret_cast<const float4*>(part + 3 * SH + i);
    float4 bb = *reinterpret_cast<const float4*>(bx + col);
    float o[4];
    {
        float xpv[4] = {xp.x, xp.y, xp.z, xp.w};
        float h0v[4] = {h0.x, h0.y, h0.z, h0.w};
        float h1v[4] = {h1.x, h1.y, h1.z, h1.w};
        float h2v[4] = {h2.x, h2.y, h2.z, h2.w};
        float h3v[4] = {h3.x, h3.y, h3.z, h3.w};
        float bv[4]  = {bb.x, bb.y, bb.z, bb.w};
        #pragma unroll
        for (int j = 0; j < 4; ++j) {
            float hcb = __fadd_rn(__fadd_rn(__fadd_rn(h0v[j], h1v[j]), h2v[j]), h3v[j]);
            float rs  = __fadd_rn(__fadd_rn(xpv[j], bv[j]), hcb);
            o[j] = xla_tanh(rs);
        }
    }
    *reinterpret_cast<float4*>(Hout + i) = make_float4(o[0], o[1], o[2], o[3]);
}

// Decoder predict partials: ppart[z] = single ascending-k chain over
// K-window [z*256, z*256+256) of H@Ml.  Tile 32 rows x 96 cols, micro 2x6.
__global__ __launch_bounds__(256)
void predict_part(const float* __restrict__ H,    // [M][1024]
                  const float* __restrict__ Ml,   // [1024][96]
                  float* __restrict__ ppart) {    // [4][M*96]
    __shared__ float lds[8576];
    float* As = lds;             // [64][34]
    float* Bs = lds + 2176;      // [64][100]

    const int tid = threadIdx.x;
    const int tx = tid & 15, ty = tid >> 4;
    const int r0 = blockIdx.x * 32;
    const int z  = blockIdx.y;

    float acc[2][6];
    #pragma unroll
    for (int i = 0; i < 2; ++i)
        #pragma unroll
        for (int j = 0; j < 6; ++j) acc[i][j] = 0.f;

    for (int kb = 0; kb < 4; ++kb) {
        const int k0 = z * 256 + kb * 64;
        __syncthreads();
        {
            int lk = tid & 63, lr0 = tid >> 6;
            #pragma unroll
            for (int i = 0; i < 8; ++i) {
                int row = lr0 + 4 * i;
                As[lk * 34 + row] = H[(size_t)(r0 + row) * 1024 + k0 + lk];
            }
        }
        #pragma unroll
        for (int i = 0; i < 24; ++i) {
            int idx = tid + 256 * i;
            int k = idx / 96, c = idx - k * 96;
            Bs[k * 100 + c] = Ml[(size_t)(k0 + k) * 96 + c];
        }
        __syncthreads();
        #pragma unroll 4
        for (int k = 0; k < 64; ++k) {
            float2 a = *reinterpret_cast<const float2*>(&As[k * 34 + ty * 2]);
            const float* bp = &Bs[k * 100 + tx * 6];
            float2 b0 = *reinterpret_cast<const float2*>(bp);
            float2 b1 = *reinterpret_cast<const float2*>(bp + 2);
            float2 b2 = *reinterpret_cast<const float2*>(bp + 4);
            float bv[6] = {b0.x, b0.y, b1.x, b1.y, b2.x, b2.y};
            #pragma unroll
            for (int j = 0; j < 6; ++j) {
                acc[0][j] = __fadd_rn(acc[0][j], __fmul_rn(a.x, bv[j]));
                acc[1][j] = __fadd_rn(acc[1][j], __fmul_rn(a.y, bv[j]));
            }
        }
    }

    float* pp = ppart + (size_t)z * (BATCH * DIN);
    #pragma unroll
    for (int i = 0; i < 2; ++i)
        #pragma unroll
        for (int j = 0; j < 6; ++j)
            pp[(size_t)(r0 + ty * 2 + i) * 96 + tx * 6 + j] = acc[i][j];
}

// pred = (((p0+p1)+p2)+p3) + bl, then normalize + Hamilton (exact R4 trees)
__global__ void combine_qmul(const float* __restrict__ ppart,
                             const float* __restrict__ bl,
                             const float* __restrict__ pre,
                             float* __restrict__ out, int M) {
    int q = blockIdx.x * blockDim.x + threadIdx.x;
    if (q >= M * 24) return;
    int b = q / 24, n = q - b * 24;
    const size_t SP = (size_t)BATCH * DIN;
    float pq[4];
    #pragma unroll
    for (int comp = 0; comp < 4; ++comp) {
        size_t idx = (size_t)b * 96 + comp * 24 + n;
        float p0 = ppart[0 * SP + idx];
        float p1 = ppart[1 * SP + idx];
        float p2 = ppart[2 * SP + idx];
        float p3 = ppart[3 * SP + idx];
        pq[comp] = __fadd_rn(__fadd_rn(__fadd_rn(__fadd_rn(p0, p1), p2), p3),
                             bl[comp * 24 + n]);
    }
    float pw = pq[0], px = pq[1], py = pq[2], pz = pq[3];
    float s = __fadd_rn(__fadd_rn(__fadd_rn(__fmul_rn(pw, pw), __fmul_rn(px, px)),
                                  __fmul_rn(py, py)), __fmul_rn(pz, pz));
    float nr = sqrtf(s);
    float nm = fmaxf(nr, 1e-12f);
    pw = __fdiv_rn(pw, nm); px = __fdiv_rn(px, nm);
    py = __fdiv_rn(py, nm); pz = __fdiv_rn(pz, nm);
    const float* r = pre + (size_t)b * 96 + n;
    float rw = r[0], rx = r[24], ry = r[48], rz = r[72];
    float* o = out + (size_t)b * 96 + n;
    o[0]  = __fsub_rn(__fsub_rn(__fsub_rn(__fmul_rn(pw, rw), __fmul_rn(px, rx)),
                                __fmul_rn(py, ry)), __fmul_rn(pz, rz));
    o[24] = __fsub_rn(__fadd_rn(__fadd_rn(__fmul_rn(pw, rx), __fmul_rn(px, rw)),
                                __fmul_rn(py, rz)), __fmul_rn(pz, ry));
    o[48] = __fadd_rn(__fadd_rn(__fsub_rn(__fmul_rn(pw, ry), __fmul_rn(px, rz)),
                                __fmul_rn(py, rw)), __fmul_rn(pz, rx));
    o[72] = __fadd_rn(__fsub_rn(__fadd_rn(__fmul_rn(pw, rz), __fmul_rn(px, ry)),
                                __fmul_rn(py, rx)), __fmul_rn(pz, rw));
}

// Encoder batched predict+qmul (verbatim R5, proven bit-exact): tile 32x96.
__global__ __launch_bounds__(256)
void predict_qmul(const float* __restrict__ H,    // [M][1024]
                  const float* __restrict__ Ml,   // [1024][96]
                  const float* __restrict__ bl,   // [96]
                  const float* __restrict__ pre,  // [M][96]
                  float* __restrict__ out) {      // [M][96]
    __shared__ float lds[8576];
    float* As = lds;             // [64][34]
    float* Bs = lds + 2176;      // [64][100]
    float* Ps = lds;             // [32][100] (aliases after GEMM)

    const int tid = threadIdx.x;
    const int tx = tid & 15, ty = tid >> 4;
    const int r0 = blockIdx.x * 32;

    float hcb[2][6], ha[2][6];
    #pragma unroll
    for (int i = 0; i < 2; ++i)
        #pragma unroll
        for (int j = 0; j < 6; ++j) { hcb[i][j] = 0.f; ha[i][j] = 0.f; }

    for (int kb = 0; kb < 16; ++kb) {
        __syncthreads();
        {
            int lk = tid & 63, lr0 = tid >> 6;
            #pragma unroll
            for (int i = 0; i < 8; ++i) {
                int row = lr0 + 4 * i;
                As[lk * 34 + row] = H[(size_t)(r0 + row) * 1024 + kb * 64 + lk];
            }
        }
        #pragma unroll
        for (int i = 0; i < 24; ++i) {
            int idx = tid + 256 * i;
            int k = idx / 96, c = idx - k * 96;
            Bs[k * 100 + c] = Ml[(size_t)(kb * 64 + k) * 96 + c];
        }
        __syncthreads();
        #pragma unroll 4
        for (int k = 0; k < 64; ++k) {
            float2 a = *reinterpret_cast<const float2*>(&As[k * 34 + ty * 2]);
            const float* bp = &Bs[k * 100 + tx * 6];
            float2 b0 = *reinterpret_cast<const float2*>(bp);
            float2 b1 = *reinterpret_cast<const float2*>(bp + 2);
            float2 b2 = *reinterpret_cast<const float2*>(bp + 4);
            float bv[6] = {b0.x, b0.y, b1.x, b1.y, b2.x, b2.y};
            #pragma unroll
            for (int j = 0; j < 6; ++j) {
                ha[0][j] = __fadd_rn(ha[0][j], __fmul_rn(a.x, bv[j]));
                ha[1][j] = __fadd_rn(ha[1][j], __fmul_rn(a.y, bv[j]));
            }
        }
        if ((kb & 3) == 3) {
            #pragma unroll
            for (int i = 0; i < 2; ++i)
                #pragma unroll
                for (int j = 0; j < 6; ++j) {
                    hcb[i][j] = __fadd_rn(hcb[i][j], ha[i][j]);
                    ha[i][j] = 0.f;
                }
        }
    }

    __syncthreads();
    #pragma unroll
    for (int i = 0; i < 2; ++i)
        #pragma unroll
        for (int j = 0; j < 6; ++j) {
            int c = tx * 6 + j;
            Ps[(ty * 2 + i) * 100 + c] = __fadd_rn(hcb[i][j], bl[c]);
        }
    __syncthreads();

    #pragma unroll
    for (int i = 0; i < 3; ++i) {
        int q = tid + 256 * i;
        int row = q / 24, n = q - row * 24;
        const float* p = &Ps[row * 100 + n];
        float pw = p[0], px = p[24], py = p[48], pz = p[72];
        float s = __fadd_rn(__fadd_rn(__fadd_rn(__fmul_rn(pw, pw), __fmul_rn(px, px)),
                                      __fmul_rn(py, py)), __fmul_rn(pz, pz));
        float nr = sqrtf(s);
        float nm = fmaxf(nr, 1e-12f);
        pw = __fdiv_rn(pw, nm); px = __fdiv_rn(px, nm);
        py = __fdiv_rn(py, nm); pz = __fdiv_rn(pz, nm);
        const float* r = pre + (size_t)(r0 + row) * 96 + n;
        float rw = r[0], rx = r[24], ry = r[48], rz = r[72];
        float* o = out + (size_t)(r0 + row) * 96 + n;
        o[0]  = __fsub_rn(__fsub_rn(__fsub_rn(__fmul_rn(pw, rw), __fmul_rn(px, rx)),
                                    __fmul_rn(py, ry)), __fmul_rn(pz, rz));
        o[24] = __fsub_rn(__fadd_rn(__fadd_rn(__fmul_rn(pw, rx), __fmul_rn(px, rw)),
                                    __fmul_rn(py, rz)), __fmul_rn(pz, ry));
        o[48] = __fadd_rn(__fadd_rn(__fsub_rn(__fmul_rn(pw, ry), __fmul_rn(px, rz)),
                                    __fmul_rn(py, rw)), __fmul_rn(pz, rx));
        o[72] = __fadd_rn(__fsub_rn(__fadd_rn(__fmul_rn(pw, rz), __fmul_rn(px, ry)),
                                    __fmul_rn(py, rx)), __fmul_rn(pz, rw));
    }
}

extern "C" void kernel_launch(void* const* d_in, const int* in_sizes, int n_in,
                              void* d_out, int out_size, void* d_ws, size_t ws_size,
                              hipStream_t stream) {
    const float* inp    = (const float*)d_in[0];
    const float* target = (const float*)d_in[1];
    const float* Wx     = (const float*)d_in[2];
    const float* bx     = (const float*)d_in[3];
    const float* Wh     = (const float*)d_in[4];
    const float* Wl     = (const float*)d_in[5];
    const float* bl     = (const float*)d_in[6];

    float* out = (float*)d_out;
    float* out_enc = out;
    float* out_dec = out + (size_t)TENC * BATCH * DIN;

    const size_t SH = (size_t)BATCH * HDIM;    // 524288
    const size_t SX = (size_t)BATCH * DIN;     // 49152

    size_t off = 0;
    auto alloc = [&](size_t nf) -> float* {
        float* p = (float*)((char*)d_ws + off);
        off += nf * sizeof(float);
        return p;
    };
    float* M_x   = alloc((size_t)DIN * HDIM);
    float* M_h   = alloc((size_t)HDIM * HDIM);
    float* M_l   = alloc((size_t)HDIM * DIN);
    float* hs    = alloc((size_t)(TENC + 1) * SH);   // 212 MB
    float* parts = alloc(5 * SH);                    // 10.5 MB
    float* ppart = alloc(4 * SX);                    // 0.8 MB

    {
        int t1 = 4 * 24 * 4 * 256;
        build_eff_kernel<<<(t1 + 255) / 256, 256, 0, stream>>>(Wx, M_x, 24, 256);
        int t2 = 4 * 256 * 4 * 256;
        build_eff_kernel<<<(t2 + 255) / 256, 256, 0, stream>>>(Wh, M_h, 256, 256);
        int t3 = 4 * 256 * 4 * 24;
        build_eff_kernel<<<(t3 + 255) / 256, 256, 0, stream>>>(Wl, M_l, 256, 24);
    }

    hipMemsetAsync(hs, 0, SH * sizeof(float), stream);  // h0 = 0

    dim3 gPart(HDIM / 64, BATCH / 64, 5);   // (16, 8, 5) = 640 wg
    const int gComb = (int)(SH / 4 / 256);  // 512 wg

    // ---- encoder ----
    for (int t = 0; t < TENC; ++t) {
        rnn_part<<<gPart, 256, 0, stream>>>(
            inp + (size_t)t * SX, hs + (size_t)t * SH, M_x, M_h, parts);
        rnn_combine<<<gComb, 256, 0, stream>>>(parts, bx, hs + (size_t)(t + 1) * SH);
    }
    predict_qmul<<<(TENC * BATCH) / 32, 256, 0, stream>>>(
        hs + SH, M_l, bl, inp, out_enc);

    // ---- decoder ----
    const float* x = target;                // target[0]
    float* hin = hs + (size_t)TENC * SH;
    dim3 gPPart(BATCH / 32, 4);             // (16, 4) = 64 wg
    for (int t = 0; t < TDEC; ++t) {
        float* hout = (t & 1) ? (hs + SH) : hs;
        rnn_part<<<gPart, 256, 0, stream>>>(x, hin, M_x, M_h, parts);
        rnn_combine<<<gComb, 256, 0, stream>>>(parts, bx, hout);
        predict_part<<<gPPart, 256, 0, stream>>>(hout, M_l, ppart);
        int nq = BATCH * 24;
        combine_qmul<<<(nq + 255) / 256, 256, 0, stream>>>(
            ppart, bl, x, out_dec + (size_t)t * SX, BATCH);
        x = out_dec + (size_t)t * SX;
        hin = hout;
    }
}

// Round 7
// 3947.612 us; speedup vs baseline: 5.0612x; 1.2597x over previous
//
#include <hip/hip_runtime.h>
#include <cstdint>

#define TENC 100
#define TDEC 25
#define BATCH 512
#define DIN 96
#define HDIM 1024

__device__ __constant__ int q_widx[4][4] = {{0,1,2,3},{1,0,3,2},{2,3,0,1},{3,2,1,0}};
__device__ __constant__ float q_sgn[4][4] = {{1.f,-1.f,-1.f,-1.f},
                                             {1.f, 1.f, 1.f,-1.f},
                                             {1.f,-1.f, 1.f, 1.f},
                                             {1.f, 1.f,-1.f, 1.f}};

// M[c*nin+m][comp*nout+o] = sgn[comp][c] * W[widx[comp][c]][m][o]
__global__ void build_eff_kernel(const float* __restrict__ W, float* __restrict__ M,
                                 int nin, int nout) {
    int idx = blockIdx.x * blockDim.x + threadIdx.x;
    int ncol = nout * 4;
    int total = nin * 4 * ncol;
    if (idx >= total) return;
    int col = idx % ncol;
    int k = idx / ncol;
    int c = k / nin, m = k - c * nin;
    int comp = col / nout, o = col - comp * nout;
    M[idx] = q_sgn[comp][c] * W[(size_t)(q_widx[comp][c] * nin + m) * nout + o];
}

// XLA-CPU f32 tanh (verified bit-matching in R4/R5/R6)
__device__ inline float xla_tanh(float x) {
    float ax = fabsf(x);
    if (ax < 0.0004f) return x;
    float t = fminf(fmaxf(x, -7.99881172180175781f), 7.99881172180175781f);
    float x2 = __fmul_rn(t, t);
    float p = -2.76076847742355e-16f;
    p = __fadd_rn(__fmul_rn(p, x2), 2.00018790482477e-13f);
    p = __fadd_rn(__fmul_rn(p, x2), -8.60467152213735e-11f);
    p = __fadd_rn(__fmul_rn(p, x2), 5.12229709037114e-08f);
    p = __fadd_rn(__fmul_rn(p, x2), 1.48572235717979e-05f);
    p = __fadd_rn(__fmul_rn(p, x2), 6.37261928875436e-04f);
    p = __fadd_rn(__fmul_rn(p, x2), 4.89352455891786e-03f);
    float num = __fmul_rn(t, p);
    float q = 1.19825839466702e-06f;
    q = __fadd_rn(__fmul_rn(q, x2), 1.18534705686654e-04f);
    q = __fadd_rn(__fmul_rn(q, x2), 2.26843463243900e-03f);
    q = __fadd_rn(__fmul_rn(q, x2), 4.89352518554385e-03f);
    return __fdiv_rn(num, q);
}

// RNN-step partials, balanced + double-buffered.
// wg (c0, r0, z) computes, for its 64x64 output tile:
//   parts[z]   = single ascending-k chain over Hin@Mh K-window [z*256, z*256+256)
//   parts[4+z] = single ascending-k chain over X@Mx  K-window [z*24,  z*24+24)
// Chain orders identical to R6 (bit-exact).  Grid (16,8,4)=512 wg, 2/CU.
__global__ __launch_bounds__(256)
void rnn_part(const float* __restrict__ X,     // [512][96]
              const float* __restrict__ Hin,   // [512][1024]
              const float* __restrict__ Mx,    // [96][1024]
              const float* __restrict__ Mh,    // [1024][1024]
              float* __restrict__ parts) {     // [8][512*1024]
    __shared__ __align__(16) float As[2][64][68];
    __shared__ __align__(16) float Bs[2][64][64];
    __shared__ __align__(16) float Xs[24][68];
    __shared__ __align__(16) float Ms[24][64];

    const int tid = threadIdx.x;
    const int tx = tid & 15, ty = tid >> 4;
    const int c0 = blockIdx.x * 64;
    const int r0 = blockIdx.y * 64;
    const int z  = blockIdx.z;                 // c-block 0..3
    const int lk = tid & 63, lr = tid >> 6;
    const size_t SH = (size_t)BATCH * HDIM;

    float areg[16], breg[16];

    // ---- prologue: issue h-chunk0 loads, stage x tiles, write LDS ----
    {
        const int k0 = z * 256;
        #pragma unroll
        for (int i = 0; i < 16; ++i)
            areg[i] = Hin[(size_t)(r0 + lr + 4 * i) * 1024 + k0 + lk];
        #pragma unroll
        for (int i = 0; i < 16; ++i)
            breg[i] = Mh[(size_t)(k0 + lr + 4 * i) * 1024 + c0 + lk];
    }
    #pragma unroll
    for (int i = 0; i < 6; ++i) {
        int idx = tid + 256 * i;               // 0..1535
        int row = idx / 24, kk = idx - row * 24;
        Xs[kk][row] = X[(size_t)(r0 + row) * 96 + z * 24 + kk];
    }
    #pragma unroll
    for (int i = 0; i < 6; ++i) {
        int idx = tid + 256 * i;
        int kk = idx >> 6, col = idx & 63;
        Ms[kk][col] = Mx[(size_t)(z * 24 + kk) * 1024 + c0 + col];
    }
    #pragma unroll
    for (int i = 0; i < 16; ++i) As[0][lk][lr + 4 * i] = areg[i];
    #pragma unroll
    for (int i = 0; i < 16; ++i) Bs[0][lr + 4 * i][lk] = breg[i];
    __syncthreads();

    // ---- x-chain: 24 ascending k (c-block z of the x-pass) ----
    {
        float xa[4][4];
        #pragma unroll
        for (int i = 0; i < 4; ++i)
            #pragma unroll
            for (int j = 0; j < 4; ++j) xa[i][j] = 0.f;
        #pragma unroll 4
        for (int kk = 0; kk < 24; ++kk) {
            float4 av = *reinterpret_cast<const float4*>(&Xs[kk][ty * 4]);
            float4 bv = *reinterpret_cast<const float4*>(&Ms[kk][tx * 4]);
            float aa[4] = {av.x, av.y, av.z, av.w};
            float bb[4] = {bv.x, bv.y, bv.z, bv.w};
            #pragma unroll
            for (int i = 0; i < 4; ++i)
                #pragma unroll
                for (int j = 0; j < 4; ++j)
                    xa[i][j] = __fadd_rn(xa[i][j], __fmul_rn(aa[i], bb[j]));
        }
        float* pp = parts + (size_t)(4 + z) * SH;
        const int ccol = c0 + tx * 4;
        #pragma unroll
        for (int i = 0; i < 4; ++i)
            *reinterpret_cast<float4*>(pp + (size_t)(r0 + ty * 4 + i) * 1024 + ccol) =
                make_float4(xa[i][0], xa[i][1], xa[i][2], xa[i][3]);
    }

    // ---- h-chain: 4 chunks of 64, double-buffered, single ascending chain ----
    float acc[4][4];
    #pragma unroll
    for (int i = 0; i < 4; ++i)
        #pragma unroll
        for (int j = 0; j < 4; ++j) acc[i][j] = 0.f;

    for (int kb = 0; kb < 4; ++kb) {
        const int cur = kb & 1;
        if (kb < 3) {                          // issue next chunk's loads early
            const int k0 = z * 256 + (kb + 1) * 64;
            #pragma unroll
            for (int i = 0; i < 16; ++i)
                areg[i] = Hin[(size_t)(r0 + lr + 4 * i) * 1024 + k0 + lk];
            #pragma unroll
            for (int i = 0; i < 16; ++i)
                breg[i] = Mh[(size_t)(k0 + lr + 4 * i) * 1024 + c0 + lk];
        }
        #pragma unroll 8
        for (int k = 0; k < 64; ++k) {
            float4 av = *reinterpret_cast<const float4*>(&As[cur][k][ty * 4]);
            float4 bv = *reinterpret_cast<const float4*>(&Bs[cur][k][tx * 4]);
            float aa[4] = {av.x, av.y, av.z, av.w};
            float bb[4] = {bv.x, bv.y, bv.z, bv.w};
            #pragma unroll
            for (int i = 0; i < 4; ++i)
                #pragma unroll
                for (int j = 0; j < 4; ++j)
                    acc[i][j] = __fadd_rn(acc[i][j], __fmul_rn(aa[i], bb[j]));
        }
        if (kb < 3) {                          // write prefetched chunk to other buf
            #pragma unroll
            for (int i = 0; i < 16; ++i) As[cur ^ 1][lk][lr + 4 * i] = areg[i];
            #pragma unroll
            for (int i = 0; i < 16; ++i) Bs[cur ^ 1][lr + 4 * i][lk] = breg[i];
            __syncthreads();
        }
    }

    float* pp = parts + (size_t)z * SH;
    const int ccol = c0 + tx * 4;
    #pragma unroll
    for (int i = 0; i < 4; ++i)
        *reinterpret_cast<float4*>(pp + (size_t)(r0 + ty * 4 + i) * 1024 + ccol) =
            make_float4(acc[i][0], acc[i][1], acc[i][2], acc[i][3]);
}

// Hout = xla_tanh( ((((x0+x1)+x2)+x3) + bx) + (((h0+h1)+h2)+h3) )
// -- exact R4/R6 fold order
__global__ __launch_bounds__(256)
void rnn_combine(const float* __restrict__ parts, const float* __restrict__ bx,
                 float* __restrict__ Hout) {
    int t = blockIdx.x * blockDim.x + threadIdx.x;
    int i = t * 4;
    int col = i & 1023;
    const size_t SH = (size_t)BATCH * HDIM;
    float4 h0 = *reinterpret_cast<const float4*>(parts + 0 * SH + i);
    float4 h1 = *reinterpret_cast<const float4*>(parts + 1 * SH + i);
    float4 h2 = *reinterpret_cast<const float4*>(parts + 2 * SH + i);
    float4 h3 = *reinterpret_cast<const float4*>(parts + 3 * SH + i);
    float4 x0 = *reinterpret_cast<const float4*>(parts + 4 * SH + i);
    float4 x1 = *reinterpret_cast<const float4*>(parts + 5 * SH + i);
    float4 x2 = *reinterpret_cast<const float4*>(parts + 6 * SH + i);
    float4 x3 = *reinterpret_cast<const float4*>(parts + 7 * SH + i);
    float4 bb = *reinterpret_cast<const float4*>(bx + col);
    float h0v[4] = {h0.x, h0.y, h0.z, h0.w};
    float h1v[4] = {h1.x, h1.y, h1.z, h1.w};
    float h2v[4] = {h2.x, h2.y, h2.z, h2.w};
    float h3v[4] = {h3.x, h3.y, h3.z, h3.w};
    float x0v[4] = {x0.x, x0.y, x0.z, x0.w};
    float x1v[4] = {x1.x, x1.y, x1.z, x1.w};
    float x2v[4] = {x2.x, x2.y, x2.z, x2.w};
    float x3v[4] = {x3.x, x3.y, x3.z, x3.w};
    float bv[4]  = {bb.x, bb.y, bb.z, bb.w};
    float o[4];
    #pragma unroll
    for (int j = 0; j < 4; ++j) {
        float xcb = __fadd_rn(__fadd_rn(__fadd_rn(x0v[j], x1v[j]), x2v[j]), x3v[j]);
        float hcb = __fadd_rn(__fadd_rn(__fadd_rn(h0v[j], h1v[j]), h2v[j]), h3v[j]);
        float rs  = __fadd_rn(__fadd_rn(xcb, bv[j]), hcb);
        o[j] = xla_tanh(rs);
    }
    *reinterpret_cast<float4*>(Hout + i) = make_float4(o[0], o[1], o[2], o[3]);
}

// Encoder batched predict+qmul: 64-row x 96-col tile, micro 4x6, 800 wg.
// Chain structure identical to R5/R6 (fold every 4 chunks = one c-block).
__global__ __launch_bounds__(256)
void predict_qmul(const float* __restrict__ H,    // [M][1024]
                  const float* __restrict__ Ml,   // [1024][96]
                  const float* __restrict__ bl,   // [96]
                  const float* __restrict__ pre,  // [M][96]
                  float* __restrict__ out) {      // [M][96]
    __shared__ float lds[10752];
    float* As = lds;             // [64][68]
    float* Bs = lds + 4352;      // [64][100]
    float* Ps = lds;             // [64][100] (aliases after GEMM)

    const int tid = threadIdx.x;
    const int tx = tid & 15, ty = tid >> 4;
    const int r0 = blockIdx.x * 64;
    const int lk = tid & 63, lr = tid >> 6;

    float hcb[4][6], ha[4][6];
    #pragma unroll
    for (int i = 0; i < 4; ++i)
        #pragma unroll
        for (int j = 0; j < 6; ++j) { hcb[i][j] = 0.f; ha[i][j] = 0.f; }

    for (int kb = 0; kb < 16; ++kb) {
        __syncthreads();
        #pragma unroll
        for (int i = 0; i < 16; ++i)
            As[lk * 68 + lr + 4 * i] = H[(size_t)(r0 + lr + 4 * i) * 1024 + kb * 64 + lk];
        #pragma unroll
        for (int i = 0; i < 24; ++i) {
            int idx = tid + 256 * i;
            int k = idx / 96, c = idx - k * 96;
            Bs[k * 100 + c] = Ml[(size_t)(kb * 64 + k) * 96 + c];
        }
        __syncthreads();
        #pragma unroll 4
        for (int k = 0; k < 64; ++k) {
            float4 av = *reinterpret_cast<const float4*>(&As[k * 68 + ty * 4]);
            const float* bp = &Bs[k * 100 + tx * 6];
            float2 b0 = *reinterpret_cast<const float2*>(bp);
            float2 b1 = *reinterpret_cast<const float2*>(bp + 2);
            float2 b2 = *reinterpret_cast<const float2*>(bp + 4);
            float aa[4] = {av.x, av.y, av.z, av.w};
            float bb[6] = {b0.x, b0.y, b1.x, b1.y, b2.x, b2.y};
            #pragma unroll
            for (int i = 0; i < 4; ++i)
                #pragma unroll
                for (int j = 0; j < 6; ++j)
                    ha[i][j] = __fadd_rn(ha[i][j], __fmul_rn(aa[i], bb[j]));
        }
        if ((kb & 3) == 3) {
            #pragma unroll
            for (int i = 0; i < 4; ++i)
                #pragma unroll
                for (int j = 0; j < 6; ++j) {
                    hcb[i][j] = __fadd_rn(hcb[i][j], ha[i][j]);
                    ha[i][j] = 0.f;
                }
        }
    }

    __syncthreads();
    #pragma unroll
    for (int i = 0; i < 4; ++i)
        #pragma unroll
        for (int j = 0; j < 6; ++j) {
            int c = tx * 6 + j;
            Ps[(ty * 4 + i) * 100 + c] = __fadd_rn(hcb[i][j], bl[c]);
        }
    __syncthreads();

    #pragma unroll
    for (int i = 0; i < 6; ++i) {
        int q = tid + 256 * i;           // 0..1535
        int row = q / 24, n = q - row * 24;
        const float* p = &Ps[row * 100 + n];
        float pw = p[0], px = p[24], py = p[48], pz = p[72];
        float s = __fadd_rn(__fadd_rn(__fadd_rn(__fmul_rn(pw, pw), __fmul_rn(px, px)),
                                      __fmul_rn(py, py)), __fmul_rn(pz, pz));
        float nr = sqrtf(s);
        float nm = fmaxf(nr, 1e-12f);
        pw = __fdiv_rn(pw, nm); px = __fdiv_rn(px, nm);
        py = __fdiv_rn(py, nm); pz = __fdiv_rn(pz, nm);
        const float* r = pre + (size_t)(r0 + row) * 96 + n;
        float rw = r[0], rx = r[24], ry = r[48], rz = r[72];
        float* o = out + (size_t)(r0 + row) * 96 + n;
        o[0]  = __fsub_rn(__fsub_rn(__fsub_rn(__fmul_rn(pw, rw), __fmul_rn(px, rx)),
                                    __fmul_rn(py, ry)), __fmul_rn(pz, rz));
        o[24] = __fsub_rn(__fadd_rn(__fadd_rn(__fmul_rn(pw, rx), __fmul_rn(px, rw)),
                                    __fmul_rn(py, rz)), __fmul_rn(pz, ry));
        o[48] = __fadd_rn(__fadd_rn(__fsub_rn(__fmul_rn(pw, ry), __fmul_rn(px, rz)),
                                    __fmul_rn(py, rw)), __fmul_rn(pz, rx));
        o[72] = __fadd_rn(__fsub_rn(__fadd_rn(__fmul_rn(pw, rz), __fmul_rn(px, ry)),
                                    __fmul_rn(py, rx)), __fmul_rn(pz, rw));
    }
}

// Decoder predict partials: ppart[z] = single ascending-k chain over
// K-window [z*256, z*256+256) of H@Ml.  16-row tiles, grid (32,4)=128 wg.
__global__ __launch_bounds__(256)
void predict_part(const float* __restrict__ H,    // [512][1024]
                  const float* __restrict__ Ml,   // [1024][96]
                  float* __restrict__ ppart) {    // [4][512*96]
    __shared__ float As[64][18];
    __shared__ float Bs[64][100];

    const int tid = threadIdx.x;
    const int tx = tid & 15, ty = tid >> 4;      // ty = row 0..15
    const int r0 = blockIdx.x * 16;
    const int z  = blockIdx.y;

    float acc[6];
    #pragma unroll
    for (int j = 0; j < 6; ++j) acc[j] = 0.f;

    for (int kb = 0; kb < 4; ++kb) {
        const int k0 = z * 256 + kb * 64;
        __syncthreads();
        #pragma unroll
        for (int i = 0; i < 4; ++i) {
            int idx = tid + 256 * i;             // 0..1023
            int k = idx & 63, row = idx >> 6;
            As[k][row] = H[(size_t)(r0 + row) * 1024 + k0 + k];
        }
        #pragma unroll
        for (int i = 0; i < 24; ++i) {
            int idx = tid + 256 * i;
            int k = idx / 96, c = idx - k * 96;
            Bs[k][c] = Ml[(size_t)(k0 + k) * 96 + c];
        }
        __syncthreads();
        #pragma unroll 8
        for (int k = 0; k < 64; ++k) {
            float a = As[k][ty];
            const float* bp = &Bs[k][tx * 6];
            float2 b0 = *reinterpret_cast<const float2*>(bp);
            float2 b1 = *reinterpret_cast<const float2*>(bp + 2);
            float2 b2 = *reinterpret_cast<const float2*>(bp + 4);
            float bb[6] = {b0.x, b0.y, b1.x, b1.y, b2.x, b2.y};
            #pragma unroll
            for (int j = 0; j < 6; ++j)
                acc[j] = __fadd_rn(acc[j], __fmul_rn(a, bb[j]));
        }
    }

    float* pp = ppart + (size_t)z * (BATCH * DIN);
    #pragma unroll
    for (int j = 0; j < 6; ++j)
        pp[(size_t)(r0 + ty) * 96 + tx * 6 + j] = acc[j];
}

// pred = (((p0+p1)+p2)+p3) + bl, then normalize + Hamilton (exact R4 trees)
__global__ void combine_qmul(const float* __restrict__ ppart,
                             const float* __restrict__ bl,
                             const float* __restrict__ pre,
                             float* __restrict__ out, int M) {
    int q = blockIdx.x * blockDim.x + threadIdx.x;
    if (q >= M * 24) return;
    int b = q / 24, n = q - b * 24;
    const size_t SP = (size_t)BATCH * DIN;
    float pq[4];
    #pragma unroll
    for (int comp = 0; comp < 4; ++comp) {
        size_t idx = (size_t)b * 96 + comp * 24 + n;
        float p0 = ppart[0 * SP + idx];
        float p1 = ppart[1 * SP + idx];
        float p2 = ppart[2 * SP + idx];
        float p3 = ppart[3 * SP + idx];
        pq[comp] = __fadd_rn(__fadd_rn(__fadd_rn(__fadd_rn(p0, p1), p2), p3),
                             bl[comp * 24 + n]);
    }
    float pw = pq[0], px = pq[1], py = pq[2], pz = pq[3];
    float s = __fadd_rn(__fadd_rn(__fadd_rn(__fmul_rn(pw, pw), __fmul_rn(px, px)),
                                  __fmul_rn(py, py)), __fmul_rn(pz, pz));
    float nr = sqrtf(s);
    float nm = fmaxf(nr, 1e-12f);
    pw = __fdiv_rn(pw, nm); px = __fdiv_rn(px, nm);
    py = __fdiv_rn(py, nm); pz = __fdiv_rn(pz, nm);
    const float* r = pre + (size_t)b * 96 + n;
    float rw = r[0], rx = r[24], ry = r[48], rz = r[72];
    float* o = out + (size_t)b * 96 + n;
    o[0]  = __fsub_rn(__fsub_rn(__fsub_rn(__fmul_rn(pw, rw), __fmul_rn(px, rx)),
                                __fmul_rn(py, ry)), __fmul_rn(pz, rz));
    o[24] = __fsub_rn(__fadd_rn(__fadd_rn(__fmul_rn(pw, rx), __fmul_rn(px, rw)),
                                __fmul_rn(py, rz)), __fmul_rn(pz, ry));
    o[48] = __fadd_rn(__fadd_rn(__fsub_rn(__fmul_rn(pw, ry), __fmul_rn(px, rz)),
                                __fmul_rn(py, rw)), __fmul_rn(pz, rx));
    o[72] = __fadd_rn(__fsub_rn(__fadd_rn(__fmul_rn(pw, rz), __fmul_rn(px, ry)),
                                __fmul_rn(py, rx)), __fmul_rn(pz, rw));
}

extern "C" void kernel_launch(void* const* d_in, const int* in_sizes, int n_in,
                              void* d_out, int out_size, void* d_ws, size_t ws_size,
                              hipStream_t stream) {
    const float* inp    = (const float*)d_in[0];
    const float* target = (const float*)d_in[1];
    const float* Wx     = (const float*)d_in[2];
    const float* bx     = (const float*)d_in[3];
    const float* Wh     = (const float*)d_in[4];
    const float* Wl     = (const float*)d_in[5];
    const float* bl     = (const float*)d_in[6];

    float* out = (float*)d_out;
    float* out_enc = out;
    float* out_dec = out + (size_t)TENC * BATCH * DIN;

    const size_t SH = (size_t)BATCH * HDIM;    // 524288
    const size_t SX = (size_t)BATCH * DIN;     // 49152

    size_t off = 0;
    auto alloc = [&](size_t nf) -> float* {
        float* p = (float*)((char*)d_ws + off);
        off += nf * sizeof(float);
        return p;
    };
    float* M_x   = alloc((size_t)DIN * HDIM);
    float* M_h   = alloc((size_t)HDIM * HDIM);
    float* M_l   = alloc((size_t)HDIM * DIN);
    float* hs    = alloc((size_t)(TENC + 1) * SH);   // 212 MB
    float* parts = alloc(8 * SH);                    // 16.8 MB
    float* ppart = alloc(4 * SX);                    // 0.8 MB

    {
        int t1 = 4 * 24 * 4 * 256;
        build_eff_kernel<<<(t1 + 255) / 256, 256, 0, stream>>>(Wx, M_x, 24, 256);
        int t2 = 4 * 256 * 4 * 256;
        build_eff_kernel<<<(t2 + 255) / 256, 256, 0, stream>>>(Wh, M_h, 256, 256);
        int t3 = 4 * 256 * 4 * 24;
        build_eff_kernel<<<(t3 + 255) / 256, 256, 0, stream>>>(Wl, M_l, 256, 24);
    }

    hipMemsetAsync(hs, 0, SH * sizeof(float), stream);  // h0 = 0

    dim3 gPart(HDIM / 64, BATCH / 64, 4);   // (16, 8, 4) = 512 wg, 2/CU exact
    const int gComb = (int)(SH / 4 / 256);  // 512 wg

    // ---- encoder ----
    for (int t = 0; t < TENC; ++t) {
        rnn_part<<<gPart, 256, 0, stream>>>(
            inp + (size_t)t * SX, hs + (size_t)t * SH, M_x, M_h, parts);
        rnn_combine<<<gComb, 256, 0, stream>>>(parts, bx, hs + (size_t)(t + 1) * SH);
    }
    predict_qmul<<<(TENC * BATCH) / 64, 256, 0, stream>>>(
        hs + SH, M_l, bl, inp, out_enc);

    // ---- decoder ----
    const float* x = target;                // target[0]
    float* hin = hs + (size_t)TENC * SH;
    dim3 gPPart(BATCH / 16, 4);             // (32, 4) = 128 wg
    for (int t = 0; t < TDEC; ++t) {
        float* hout = (t & 1) ? (hs + SH) : hs;
        rnn_part<<<gPart, 256, 0, stream>>>(x, hin, M_x, M_h, parts);
        rnn_combine<<<gComb, 256, 0, stream>>>(parts, bx, hout);
        predict_part<<<gPPart, 256, 0, stream>>>(hout, M_l, ppart);
        int nq = BATCH * 24;
        combine_qmul<<<(nq + 255) / 256, 256, 0, stream>>>(
            ppart, bl, x, out_dec + (size_t)t * SX, BATCH);
        x = out_dec + (size_t)t * SX;
        hin = hout;
    }
}